// Round 17
// baseline (121.027 us; speedup 1.0000x reference)
//
#include <hip/hip_runtime.h>
#include <hip/hip_bf16.h>

// Problem constants
// B=8, C=64, H=256, W=256, NH=4, O=16 (HO=64), MX=32, MY=17
#define NROWS 131072
#define MY 17
#define MX 32

// ws layout (floats):
//   X2:   [4456960, +557056)   [(b*64+c)*32+kx][ky] float2

// ---------------------------------------------------------------------------
// F1 = K1+K2 fused, one (b,c) plane per block, 512 threads.
//  K1 j-PAIRED: thread computes modes (j0, j0+2) (same parity -> same LDS
//  planes, sign-flipped combine consts). 9 groups/row instead of 17 ->
//  K1-phase LDS reads halved. Planes padded to 2044 floats (bank spread).
//  K2 kx-PAIRED: (kx0, kx0+2) share all LDS reads; yre1 = 2a.x - yre0.
// ---------------------------------------------------------------------------
#define K1_ROWS 30
#define NCHUNK 9     // 8*30 + 16 = 256
#define PLANE 2044   // 30*68 + 4 pad floats

__global__ __launch_bounds__(512) void f1_fw(const float* __restrict__ x,
                                             float2* __restrict__ X2) {
    __shared__ __align__(16) float s_lds[4 * PLANE];   // 32704 B
    __shared__ float2 xs[4352];                        // 34816 B  [h*17+ky]
    int t = threadIdx.x;
    int bc = blockIdx.x;  // 0..511
    const float* xp = x + (long)bc * 65536;

    // K1 compute mapping: t<270: g = t/9 (row), e = t%9 (j-pair group)
    // e<5: even modes j0 = 4e (16's pair j1=18 is computed, not stored)
    // e>=5: odd modes j0 = 4e-19 (1,5,9,13), j1 = j0+2
    int g = t / 9;
    int e = t % 9;
    int odd = (e >= 5);
    int j0 = odd ? 4 * e - 19 : 4 * e;
    int j1 = j0 + 2;
    float ca = odd ? 0.f : 1.f;    // ca(j0); ca(j1) = -ca
    float cb = odd ? -1.f : 0.f;   // cb(j0); cb(j1) = -cb
    float cj0, sj0, cj1, sj1;
    sincospif((float)j0 * (1.0f / 128.0f), &sj0, &cj0); sj0 = -sj0;
    sincospif((float)j1 * (1.0f / 128.0f), &sj1, &cj1); sj1 = -sj1;
    float c80, s80, c81, s81;
    sincospif((float)j0 * 0.25f, &s80, &c80); s80 = -s80;  // e^{-pi i j0/4}
    sincospif((float)j1 * 0.25f, &s81, &c81); s81 = -s81;
    const float4* A4 = (const float4*)(s_lds + (odd ? PLANE : 0) + g * 68);
    const float4* B4 = (const float4*)(s_lds + (odd ? 3 * PLANE : 2 * PLANE) + g * 68);

    float4 q0, q1, q2, q3;

#define F1_REGLOAD(cc)                                                         \
    {                                                                          \
        int nr_ = ((cc) < 8) ? K1_ROWS : 16;                                   \
        int items_ = nr_ * 16;                                                 \
        int it = t < items_ ? t : items_ - 1;                                  \
        int rr = it >> 4, cq = it & 15;                                        \
        const float4* xr =                                                     \
            (const float4*)(xp + ((cc) * K1_ROWS + rr) * 256) + cq;            \
        q0 = xr[0];                                                            \
        q1 = xr[16];                                                           \
        q2 = xr[32];                                                           \
        q3 = xr[48];                                                           \
    }

    F1_REGLOAD(0)

    for (int c = 0; c < NCHUNK; ++c) {
        int nr = (c < 8) ? K1_ROWS : 16;
        int items = nr * 16;

        // radix-4 combine (along w) + LDS write, from registers
        if (t < items) {
            int rr = t >> 4, cq = t & 15;
            float4 s02p, s02m, s13p, s13m;
            s02p.x = q0.x + q2.x; s02p.y = q0.y + q2.y;
            s02p.z = q0.z + q2.z; s02p.w = q0.w + q2.w;
            s02m.x = q0.x - q2.x; s02m.y = q0.y - q2.y;
            s02m.z = q0.z - q2.z; s02m.w = q0.w - q2.w;
            s13p.x = q1.x + q3.x; s13p.y = q1.y + q3.y;
            s13p.z = q1.z + q3.z; s13p.w = q1.w + q3.w;
            s13m.x = q1.x - q3.x; s13m.y = q1.y - q3.y;
            s13m.z = q1.z - q3.z; s13m.w = q1.w - q3.w;
            int base = rr * 68 + cq * 4;
            *(float4*)&s_lds[base]             = s02p;
            *(float4*)&s_lds[PLANE + base]     = s02m;
            *(float4*)&s_lds[2 * PLANE + base] = s13p;
            *(float4*)&s_lds[3 * PLANE + base] = s13m;
        }
        __syncthreads();

        // prefetch next chunk into registers (in flight during compute)
        if (c + 1 < NCHUNK) F1_REGLOAD(c + 1)

        // paired 17-mode DFT (radix-2 over l), 2 modes per thread, 1 row
        if (t < 270 && g < nr) {
            float pc0 = 1.f, ps0 = 0.f, pc1 = 1.f, ps1 = 0.f;
            float ar0 = 0, ai0 = 0, ar1 = 0, ai1 = 0;

#define K1_STEP(aL, bL, aH, bH)                                        \
  { float y0Lre = fmaf(ca, (bL), (aL));                                \
    float y0Lim = cb * (bL);                                           \
    float y1Lre = fmaf(-ca, (bL), (aL));                               \
    float y0Hre = fmaf(ca, (bH), (aH));                                \
    float y0Him = cb * (bH);                                           \
    float y1Hre = fmaf(-ca, (bH), (aH));                               \
    float t0re = fmaf(-s80, y0Him, fmaf(c80, y0Hre, y0Lre));           \
    float t0im = fmaf(s80, y0Hre, fmaf(c80, y0Him, y0Lim));            \
    float t1re = fmaf(s81, y0Him, fmaf(c81, y1Hre, y1Lre));            \
    float t1im = fmaf(s81, y1Hre, fmaf(-c81, y0Him, -y0Lim));          \
    ar0 = fmaf(t0re, pc0, ar0); ar0 = fmaf(-t0im, ps0, ar0);           \
    ai0 = fmaf(t0re, ps0, ai0); ai0 = fmaf(t0im, pc0, ai0);            \
    ar1 = fmaf(t1re, pc1, ar1); ar1 = fmaf(-t1im, ps1, ar1);           \
    ai1 = fmaf(t1re, ps1, ai1); ai1 = fmaf(t1im, pc1, ai1);            \
    float nps0 = fmaf(pc0, sj0, ps0 * cj0);                            \
    pc0 = fmaf(pc0, cj0, -(ps0 * sj0)); ps0 = nps0;                    \
    float nps1 = fmaf(pc1, sj1, ps1 * cj1);                            \
    pc1 = fmaf(pc1, cj1, -(ps1 * sj1)); ps1 = nps1; }

#pragma unroll 2
            for (int l4 = 0; l4 < 8; ++l4) {
                float4 va = A4[l4], vb = B4[l4];
                float4 vA = A4[8 + l4], vB = B4[8 + l4];  // l+32
                K1_STEP(va.x, vb.x, vA.x, vB.x)
                K1_STEP(va.y, vb.y, vA.y, vB.y)
                K1_STEP(va.z, vb.z, vA.z, vB.z)
                K1_STEP(va.w, vb.w, vA.w, vB.w)
            }
#undef K1_STEP

            int h = c * K1_ROWS + g;
            xs[h * 17 + j0] = make_float2(ar0, ai0);
            if (j1 < 17) xs[h * 17 + j1] = make_float2(ar1, ai1);
        }
        __syncthreads();
    }

    // K2: in-place radix-4 butterfly along h (stage 1: h vs h+128)
    for (int q = t; q < 2176; q += 512) {
        float2 a = xs[q], b = xs[q + 2176];
        xs[q] = make_float2(a.x + b.x, a.y + b.y);
        xs[q + 2176] = make_float2(a.x - b.x, a.y - b.y);
    }
    __syncthreads();
    // xs[0..1087]=u02p, [1088..2175]=u13p, [2176..3263]=u02m, [3264..4351]=u13m

    // K2 paired: thread owns (kx0, kx0+2, ky); all LDS reads shared
    if (t < 272) {
        int grp = t / 17, ky = t % 17;
        int kodd = (grp >= 8);
        int kx0 = kodd ? 4 * (grp - 8) + 1 : 4 * grp;
        int kx1 = kx0 + 2;
        float cA = kodd ? 0.f : 1.f;   // cA(kx0); cA(kx1) = -cA
        float cB = kodd ? -1.f : 0.f;  // cB(kx0); cB(kx1) = -cB
        float cs0, ss0, cs1, ss1;
        sincospif((float)kx0 * (1.0f / 128.0f), &ss0, &cs0); ss0 = -ss0;
        sincospif((float)kx1 * (1.0f / 128.0f), &ss1, &cs1); ss1 = -ss1;
        const float2* Aq = xs + (kodd ? 2176 : 0) + ky;
        float pc0 = 1.f, ps0 = 0.f, pc1 = 1.f, ps1 = 0.f;
        float ar0 = 0, ai0 = 0, ar1 = 0, ai1 = 0;
#pragma unroll 4
        for (int m = 0; m < 64; ++m) {
            float2 a = Aq[m * 17];
            float2 b = Aq[1088 + m * 17];
            float yre0 = fmaf(-cB, b.y, fmaf(cA, b.x, a.x));
            float yim0 = fmaf(cB, b.x, fmaf(cA, b.y, a.y));
            float yre1 = fmaf(2.f, a.x, -yre0);
            float yim1 = fmaf(2.f, a.y, -yim0);
            ar0 = fmaf(yre0, pc0, ar0); ar0 = fmaf(-yim0, ps0, ar0);
            ai0 = fmaf(yre0, ps0, ai0); ai0 = fmaf(yim0, pc0, ai0);
            ar1 = fmaf(yre1, pc1, ar1); ar1 = fmaf(-yim1, ps1, ar1);
            ai1 = fmaf(yre1, ps1, ai1); ai1 = fmaf(yim1, pc1, ai1);
            float nps0 = fmaf(pc0, ss0, ps0 * cs0);
            pc0 = fmaf(pc0, cs0, -(ps0 * ss0)); ps0 = nps0;
            float nps1 = fmaf(pc1, ss1, ps1 * cs1);
            pc1 = fmaf(pc1, cs1, -(ps1 * ss1)); ps1 = nps1;
        }
        X2[(long)bc * 544 + kx0 * 17 + ky] = make_float2(ar0, ai0);
        X2[(long)bc * 544 + kx1 * 17 + ky] = make_float2(ar1, ai1);
    }
#undef F1_REGLOAD
}

// ---------------------------------------------------------------------------
// F2C = k3+K4+K5 fused, one (b,ho) plane per block, 512 threads. (R14 exact)
// ---------------------------------------------------------------------------
__global__ __launch_bounds__(512) void f2c_inv(const float2* __restrict__ X2,
                                               const float* __restrict__ wr_g,
                                               const float* __restrict__ wi_g,
                                               const float* __restrict__ bias,
                                               float* __restrict__ out) {
    __shared__ float2 psh[544];
    __shared__ float2 zsh[4352];  // [h*17+ky]
    int t = threadIdx.x;
    int plane = blockIdx.x;  // 0..511 = b*64 + ho
    int b = plane >> 6;
    int ho = plane & 63;
    int n = ho >> 4;
    int o = ho & 15;

    // Phase A: per-(kx,ky) 64-deep channel reduction, 2 accumulator pairs
    for (int q = t; q < 544; q += 512) {
        const float2* xp = X2 + (long)b * 64 * 544 + q;
        const float* wrp = wr_g + ((long)(n * 64) * 16 + o) * 544 + q;
        const float* wip = wi_g + ((long)(n * 64) * 16 + o) * 544 + q;
        float ar = 0.f, ai = 0.f, ar2 = 0.f, ai2 = 0.f;
#pragma unroll 4
        for (int i = 0; i < 64; i += 2) {
            float2 xv0 = xp[i * 544];
            float w0r = wrp[i * 8704];
            float w0i = wip[i * 8704];
            float2 xv1 = xp[(i + 1) * 544];
            float w1r = wrp[(i + 1) * 8704];
            float w1i = wip[(i + 1) * 8704];
            ar = fmaf(xv0.x, w0r, fmaf(-xv0.y, w0i, ar));
            ai = fmaf(xv0.x, w0i, fmaf(xv0.y, w0r, ai));
            ar2 = fmaf(xv1.x, w1r, fmaf(-xv1.y, w1i, ar2));
            ai2 = fmaf(xv1.x, w1i, fmaf(xv1.y, w1r, ai2));
        }
        psh[q] = make_float2(ar + ar2, ai + ai2);
    }
    __syncthreads();

    // Phase B: h-pair radix-2 over kx. h = t&127, pair (h, h+128). (verified)
    {
        int h = t & 127;
        int grp = t >> 7;                        // 0..3, wave-uniform
        int kyb = (grp == 0) ? 0 : (4 * grp + 1);  // 0,5,9,13
        int cnt = (grp == 0) ? 5 : 4;
        float chh, shh;
        sincospif((float)h * (1.0f / 128.0f), &shh, &chh);  // step e^{+2pi i h/256}
        float pc = 1.f, psn = 0.f;
        float aer[5], aei[5], aor[5], aoi[5];
#pragma unroll
        for (int u = 0; u < 5; ++u) { aer[u] = 0.f; aei[u] = 0.f; aor[u] = 0.f; aoi[u] = 0.f; }

        const float2* pq = psh + kyb;
#pragma unroll
        for (int kx = 0; kx < 32; ++kx) {
#pragma unroll
            for (int u = 0; u < 5; ++u) {
                if (u < cnt) {
                    float2 v = pq[kx * 17 + u];
                    if ((kx & 1) == 0) {
                        aer[u] = fmaf(v.x, pc, fmaf(-v.y, psn, aer[u]));
                        aei[u] = fmaf(v.x, psn, fmaf(v.y, pc, aei[u]));
                    } else {
                        aor[u] = fmaf(v.x, pc, fmaf(-v.y, psn, aor[u]));
                        aoi[u] = fmaf(v.x, psn, fmaf(v.y, pc, aoi[u]));
                    }
                }
            }
            float npc = pc * chh - psn * shh;
            psn = pc * shh + psn * chh;
            pc = npc;
        }
#pragma unroll
        for (int u = 0; u < 5; ++u) {
            if (u < cnt) {
                int ky = kyb + u;
                zsh[h * 17 + ky] = make_float2(aer[u] + aor[u], aei[u] + aoi[u]);
                zsh[(h + 128) * 17 + ky] = make_float2(aer[u] - aor[u], aei[u] - aoi[u]);
            }
        }
    }
    __syncthreads();

    // Phase C: wide read + readlane (z is wave-uniform), ky-fold, hoisted table
    int wv = t >> 6;      // 0..7
    int lane = t & 63;
    float bv = bias[plane & 63];
    float c0, s0;
    sincospif((float)lane * (1.0f / 128.0f), &s0, &c0);  // e^{2pi i lane/256}
    float c8, s8;
    sincospif((float)lane * (1.0f / 16.0f), &s8, &c8);   // e^{2pi i 8 lane/256}

    float pcv[8], psv[8];
    {
        float pc = c0, ps = s0;
#pragma unroll
        for (int k = 0; k < 8; ++k) {
            pcv[k] = pc; psv[k] = ps;
            float nps = fmaf(pc, s0, ps * c0);
            pc = fmaf(pc, c0, -(ps * s0));
            ps = nps;
        }
    }

    const float inv = 1.0f / 65536.0f;
    const float inv2 = 2.0f / 65536.0f;
    long ob_plane = (long)plane * 65536;
    int li = lane < 34 ? lane : 33;

    for (int it16 = 0; it16 < 16; ++it16) {
        int r0 = it16 * 16 + wv * 2;
        // one wide read covers rows r0 and r0+1: zsh[r0*17 + 0..33]
        float2 zl = zsh[r0 * 17 + li];
        float zlx = zl.x, zly = zl.y;

#define RLF(v, l) __int_as_float(__builtin_amdgcn_readlane(__float_as_int(v), (l)))
        float zz0r[8], zz0i[8], zz1r[8], zz1i[8];
#pragma unroll
        for (int k = 0; k < 8; ++k) {
            float a0r = RLF(zlx, k + 1),  a0i = RLF(zly, k + 1);
            float b0r = RLF(zlx, k + 9),  b0i = RLF(zly, k + 9);
            float a1r = RLF(zlx, 18 + k), a1i = RLF(zly, 18 + k);
            float b1r = RLF(zlx, 26 + k), b1i = RLF(zly, 26 + k);
            zz0r[k] = fmaf(b0r, c8, fmaf(-b0i, s8, a0r));
            zz0i[k] = fmaf(b0r, s8, fmaf(b0i, c8, a0i));
            zz1r[k] = fmaf(b1r, c8, fmaf(-b1i, s8, a1r));
            zz1i[k] = fmaf(b1r, s8, fmaf(b1i, c8, a1i));
        }
        float base0 = RLF(zlx, 0) * inv + bv;
        float base1 = RLF(zlx, 17) * inv + bv;
#undef RLF

        float a00 = 0, a01 = 0, a02 = 0, a03 = 0;
        float a10 = 0, a11 = 0, a12 = 0, a13 = 0;
#pragma unroll
        for (int k = 0; k < 8; ++k) {
            int ky = k + 1;
            float A0 = zz0r[k] * pcv[k] - zz0i[k] * psv[k];
            float B0 = zz0r[k] * psv[k] + zz0i[k] * pcv[k];
            float A1 = zz1r[k] * pcv[k] - zz1i[k] * psv[k];
            float B1 = zz1r[k] * psv[k] + zz1i[k] * pcv[k];
            a00 += A0; a10 += A1;
            a01 += ((ky & 3) == 0) ? A0 : ((ky & 3) == 1) ? -B0 : ((ky & 3) == 2) ? -A0 : B0;
            a11 += ((ky & 3) == 0) ? A1 : ((ky & 3) == 1) ? -B1 : ((ky & 3) == 2) ? -A1 : B1;
            a02 += (ky & 1) ? -A0 : A0;
            a12 += (ky & 1) ? -A1 : A1;
            a03 += ((ky & 3) == 0) ? A0 : ((ky & 3) == 1) ? B0 : ((ky & 3) == 2) ? -A0 : -B0;
            a13 += ((ky & 3) == 0) ? A1 : ((ky & 3) == 1) ? B1 : ((ky & 3) == 2) ? -A1 : -B1;
        }
        long ob0 = ob_plane + (long)r0 * 256;
        long ob1 = ob0 + 256;
        out[ob0 + lane]       = fmaf(a00, inv2, base0);
        out[ob0 + 64 + lane]  = fmaf(a01, inv2, base0);
        out[ob0 + 128 + lane] = fmaf(a02, inv2, base0);
        out[ob0 + 192 + lane] = fmaf(a03, inv2, base0);
        out[ob1 + lane]       = fmaf(a10, inv2, base1);
        out[ob1 + 64 + lane]  = fmaf(a11, inv2, base1);
        out[ob1 + 128 + lane] = fmaf(a12, inv2, base1);
        out[ob1 + 192 + lane] = fmaf(a13, inv2, base1);
    }
}

extern "C" void kernel_launch(void* const* d_in, const int* in_sizes, int n_in,
                              void* d_out, int out_size, void* d_ws, size_t ws_size,
                              hipStream_t stream) {
    const float* x = (const float*)d_in[0];
    const float* wr = (const float*)d_in[1];
    const float* wi = (const float*)d_in[2];
    const float* bias = (const float*)d_in[3];
    float* out = (float*)d_out;
    float* ws = (float*)d_ws;

    float2* X2 = (float2*)(ws + 4456960);

    hipLaunchKernelGGL(f1_fw, dim3(512), dim3(512), 0, stream, x, X2);
    hipLaunchKernelGGL(f2c_inv, dim3(512), dim3(512), 0, stream, X2, wr, wi, bias, out);
}

// Round 18
// 112.600 us; speedup vs baseline: 1.0748x; 1.0748x over previous
//
#include <hip/hip_runtime.h>
#include <hip/hip_bf16.h>

// Problem constants
// B=8, C=64, H=256, W=256, NH=4, O=16 (HO=64), MX=32, MY=17
#define NROWS 131072
#define MY 17
#define MX 32

// ws layout (floats):
//   X2:   [4456960, +557056)   [(b*64+c)*32+kx][ky] float2

// ---------------------------------------------------------------------------
// F1 = K1+K2 fused, one (b,c) plane per block, 512 threads.
//  K1 j-PAIR + l-SPLIT: thread (g row, e pair-group, half):
//   - modes (j0, j0+2): same parity -> same LDS planes (R16 verified math)
//   - half h sums l = 16h..16h+15 (initial phasor e^{-i pi j h/8}),
//     partials combined via __shfl_xor lane^1 (pairs are adjacent lanes)
//  => LDS reads/thread halved vs R8, per-thread VALU ~equal, 8 waves live.
//  K2 + butterfly: R8-exact (verified).
// ---------------------------------------------------------------------------
#define K1_ROWS 28
#define NCHUNK 10    // 9*28 = 252 + 4

__global__ __launch_bounds__(512) void f1_fw(const float* __restrict__ x,
                                             float2* __restrict__ X2) {
    __shared__ __align__(16) float s_lds[4][K1_ROWS][68];  // 30464 B
    __shared__ float2 xs[4352];                            // 34816 B  [h*17+ky]
    int t = threadIdx.x;
    int bc = blockIdx.x;  // 0..511
    const float* xp = x + (long)bc * 65536;

    // K1 mapping: t<504: half = t&1, u = t>>1, e = u%9 (j-pair), g = u/9 (row)
    int half = t & 1;
    int u = t >> 1;
    int e = u % 9;
    int g = u / 9;           // 0..27
    int odd = (e >= 5);
    int j0 = odd ? 4 * e - 19 : 4 * e;   // even: 0,4,8,12,16; odd: 1,5,9,13
    int j1 = j0 + 2;
    float ca = odd ? 0.f : 1.f;    // ca(j0); ca(j1) = -ca
    float cb = odd ? -1.f : 0.f;   // cb(j0); cb(j1) = -cb
    float cj0, sj0, cj1, sj1;
    sincospif((float)j0 * (1.0f / 128.0f), &sj0, &cj0); sj0 = -sj0;
    sincospif((float)j1 * (1.0f / 128.0f), &sj1, &cj1); sj1 = -sj1;
    float c80, s80, c81, s81;
    sincospif((float)j0 * 0.25f, &s80, &c80); s80 = -s80;  // e^{-pi i j0/4}
    sincospif((float)j1 * 0.25f, &s81, &c81); s81 = -s81;
    // initial phasors at l = 16*half: e^{-pi i j*half/8}
    float ip0c, ip0s, ip1c, ip1s;
    sincospif((float)(j0 * half) * 0.125f, &ip0s, &ip0c); ip0s = -ip0s;
    sincospif((float)(j1 * half) * 0.125f, &ip1s, &ip1c); ip1s = -ip1s;
    const float4* A4 = (const float4*)&s_lds[odd ? 1 : 0][g < K1_ROWS ? g : 0][0];
    const float4* B4 = (const float4*)&s_lds[odd ? 3 : 2][g < K1_ROWS ? g : 0][0];
    int l4b = half * 4;

    float4 q0, q1, q2, q3;

#define F1_REGLOAD(cc)                                                         \
    {                                                                          \
        int nr_ = ((cc) < 9) ? K1_ROWS : 4;                                    \
        int items_ = nr_ * 16;                                                 \
        int it = t < items_ ? t : items_ - 1;                                  \
        int rr = it >> 4, cq = it & 15;                                        \
        const float4* xr =                                                     \
            (const float4*)(xp + ((cc) * K1_ROWS + rr) * 256) + cq;            \
        q0 = xr[0];                                                            \
        q1 = xr[16];                                                           \
        q2 = xr[32];                                                           \
        q3 = xr[48];                                                           \
    }

    F1_REGLOAD(0)

    for (int c = 0; c < NCHUNK; ++c) {
        int nr = (c < 9) ? K1_ROWS : 4;
        int items = nr * 16;

        // radix-4 combine (along w) + LDS write, from registers
        if (t < items) {
            int rr = t >> 4, cq = t & 15;
            float4 s02p, s02m, s13p, s13m;
            s02p.x = q0.x + q2.x; s02p.y = q0.y + q2.y;
            s02p.z = q0.z + q2.z; s02p.w = q0.w + q2.w;
            s02m.x = q0.x - q2.x; s02m.y = q0.y - q2.y;
            s02m.z = q0.z - q2.z; s02m.w = q0.w - q2.w;
            s13p.x = q1.x + q3.x; s13p.y = q1.y + q3.y;
            s13p.z = q1.z + q3.z; s13p.w = q1.w + q3.w;
            s13m.x = q1.x - q3.x; s13m.y = q1.y - q3.y;
            s13m.z = q1.z - q3.z; s13m.w = q1.w - q3.w;
            *(float4*)&s_lds[0][rr][cq * 4] = s02p;
            *(float4*)&s_lds[1][rr][cq * 4] = s02m;
            *(float4*)&s_lds[2][rr][cq * 4] = s13p;
            *(float4*)&s_lds[3][rr][cq * 4] = s13m;
        }
        __syncthreads();

        // prefetch next chunk into registers (in flight during compute)
        if (c + 1 < NCHUNK) F1_REGLOAD(c + 1)

        // paired DFT, 16 l-steps per thread (half of the 32-step radix-2 sum)
        {
            float pc0 = ip0c, ps0 = ip0s, pc1 = ip1c, ps1 = ip1s;
            float ar0 = 0, ai0 = 0, ar1 = 0, ai1 = 0;

#define K1_STEP(aL, bL, aH, bH)                                        \
  { float y0Lre = fmaf(ca, (bL), (aL));                                \
    float y0Lim = cb * (bL);                                           \
    float y1Lre = fmaf(-ca, (bL), (aL));                               \
    float y0Hre = fmaf(ca, (bH), (aH));                                \
    float y0Him = cb * (bH);                                           \
    float y1Hre = fmaf(-ca, (bH), (aH));                               \
    float t0re = fmaf(-s80, y0Him, fmaf(c80, y0Hre, y0Lre));           \
    float t0im = fmaf(s80, y0Hre, fmaf(c80, y0Him, y0Lim));            \
    float t1re = fmaf(s81, y0Him, fmaf(c81, y1Hre, y1Lre));            \
    float t1im = fmaf(s81, y1Hre, fmaf(-c81, y0Him, -y0Lim));          \
    ar0 = fmaf(t0re, pc0, ar0); ar0 = fmaf(-t0im, ps0, ar0);           \
    ai0 = fmaf(t0re, ps0, ai0); ai0 = fmaf(t0im, pc0, ai0);            \
    ar1 = fmaf(t1re, pc1, ar1); ar1 = fmaf(-t1im, ps1, ar1);           \
    ai1 = fmaf(t1re, ps1, ai1); ai1 = fmaf(t1im, pc1, ai1);            \
    float nps0 = fmaf(pc0, sj0, ps0 * cj0);                            \
    pc0 = fmaf(pc0, cj0, -(ps0 * sj0)); ps0 = nps0;                    \
    float nps1 = fmaf(pc1, sj1, ps1 * cj1);                            \
    pc1 = fmaf(pc1, cj1, -(ps1 * sj1)); ps1 = nps1; }

            bool act = (t < 504) && (g < nr);
            if (act) {
#pragma unroll
                for (int k = 0; k < 4; ++k) {
                    float4 va = A4[l4b + k], vb = B4[l4b + k];
                    float4 vA = A4[8 + l4b + k], vB = B4[8 + l4b + k];  // l+32
                    K1_STEP(va.x, vb.x, vA.x, vB.x)
                    K1_STEP(va.y, vb.y, vA.y, vB.y)
                    K1_STEP(va.z, vb.z, vA.z, vB.z)
                    K1_STEP(va.w, vb.w, vA.w, vB.w)
                }
            }
#undef K1_STEP
            // combine the two l-halves (pairs are adjacent lanes t, t^1)
            ar0 += __shfl_xor(ar0, 1);
            ai0 += __shfl_xor(ai0, 1);
            ar1 += __shfl_xor(ar1, 1);
            ai1 += __shfl_xor(ai1, 1);
            if (act && half == 0) {
                int h = c * K1_ROWS + g;
                xs[h * 17 + j0] = make_float2(ar0, ai0);
                if (j1 < 17) xs[h * 17 + j1] = make_float2(ar1, ai1);
            }
        }
        __syncthreads();
    }

    // K2: in-place radix-4 butterfly along h (stage 1: h vs h+128)  (R8 exact)
    for (int q = t; q < 2176; q += 512) {
        float2 a = xs[q], b = xs[q + 2176];
        xs[q] = make_float2(a.x + b.x, a.y + b.y);
        xs[q + 2176] = make_float2(a.x - b.x, a.y - b.y);
    }
    __syncthreads();

    for (int q = t; q < 544; q += 512) {
        int kx = q / 17, ky = q % 17;
        int kodd = kx & 1;
        float cA = kodd ? 0.f : ((kx & 2) ? -1.f : 1.f);
        float cB = kodd ? (((kx & 3) == 1) ? -1.f : 1.f) : 0.f;
        float cBn = -cB;
        const float2* Aq = xs + (kodd ? 2176 : 0) + ky;
        float cs, ss;
        sincospif((float)kx * (1.0f / 128.0f), &ss, &cs);
        ss = -ss;  // step e^{-2pi i kx/256}
        float pc = 1.f, psn = 0.f;
        float ar = 0.f, ai = 0.f;
#pragma unroll 4
        for (int m = 0; m < 64; ++m) {
            float2 a = Aq[m * 17];
            float2 b = Aq[1088 + m * 17];
            float yre = fmaf(cBn, b.y, fmaf(cA, b.x, a.x));
            float yim = fmaf(cB, b.x, fmaf(cA, b.y, a.y));
            ar = fmaf(yre, pc, ar); ar = fmaf(-yim, psn, ar);
            ai = fmaf(yre, psn, ai); ai = fmaf(yim, pc, ai);
            float npc = pc * cs - psn * ss;
            psn = pc * ss + psn * cs;
            pc = npc;
        }
        X2[(long)bc * 544 + q] = make_float2(ar, ai);
    }
#undef F1_REGLOAD
}

// ---------------------------------------------------------------------------
// F2C = k3+K4+K5 fused, one (b,ho) plane per block, 512 threads. (R14 exact)
// ---------------------------------------------------------------------------
__global__ __launch_bounds__(512) void f2c_inv(const float2* __restrict__ X2,
                                               const float* __restrict__ wr_g,
                                               const float* __restrict__ wi_g,
                                               const float* __restrict__ bias,
                                               float* __restrict__ out) {
    __shared__ float2 psh[544];
    __shared__ float2 zsh[4352];  // [h*17+ky]
    int t = threadIdx.x;
    int plane = blockIdx.x;  // 0..511 = b*64 + ho
    int b = plane >> 6;
    int ho = plane & 63;
    int n = ho >> 4;
    int o = ho & 15;

    // Phase A: per-(kx,ky) 64-deep channel reduction, 2 accumulator pairs
    for (int q = t; q < 544; q += 512) {
        const float2* xp = X2 + (long)b * 64 * 544 + q;
        const float* wrp = wr_g + ((long)(n * 64) * 16 + o) * 544 + q;
        const float* wip = wi_g + ((long)(n * 64) * 16 + o) * 544 + q;
        float ar = 0.f, ai = 0.f, ar2 = 0.f, ai2 = 0.f;
#pragma unroll 4
        for (int i = 0; i < 64; i += 2) {
            float2 xv0 = xp[i * 544];
            float w0r = wrp[i * 8704];
            float w0i = wip[i * 8704];
            float2 xv1 = xp[(i + 1) * 544];
            float w1r = wrp[(i + 1) * 8704];
            float w1i = wip[(i + 1) * 8704];
            ar = fmaf(xv0.x, w0r, fmaf(-xv0.y, w0i, ar));
            ai = fmaf(xv0.x, w0i, fmaf(xv0.y, w0r, ai));
            ar2 = fmaf(xv1.x, w1r, fmaf(-xv1.y, w1i, ar2));
            ai2 = fmaf(xv1.x, w1i, fmaf(xv1.y, w1r, ai2));
        }
        psh[q] = make_float2(ar + ar2, ai + ai2);
    }
    __syncthreads();

    // Phase B: h-pair radix-2 over kx. h = t&127, pair (h, h+128). (verified)
    {
        int h = t & 127;
        int grp = t >> 7;                        // 0..3, wave-uniform
        int kyb = (grp == 0) ? 0 : (4 * grp + 1);  // 0,5,9,13
        int cnt = (grp == 0) ? 5 : 4;
        float chh, shh;
        sincospif((float)h * (1.0f / 128.0f), &shh, &chh);  // step e^{+2pi i h/256}
        float pc = 1.f, psn = 0.f;
        float aer[5], aei[5], aor[5], aoi[5];
#pragma unroll
        for (int u = 0; u < 5; ++u) { aer[u] = 0.f; aei[u] = 0.f; aor[u] = 0.f; aoi[u] = 0.f; }

        const float2* pq = psh + kyb;
#pragma unroll
        for (int kx = 0; kx < 32; ++kx) {
#pragma unroll
            for (int u = 0; u < 5; ++u) {
                if (u < cnt) {
                    float2 v = pq[kx * 17 + u];
                    if ((kx & 1) == 0) {
                        aer[u] = fmaf(v.x, pc, fmaf(-v.y, psn, aer[u]));
                        aei[u] = fmaf(v.x, psn, fmaf(v.y, pc, aei[u]));
                    } else {
                        aor[u] = fmaf(v.x, pc, fmaf(-v.y, psn, aor[u]));
                        aoi[u] = fmaf(v.x, psn, fmaf(v.y, pc, aoi[u]));
                    }
                }
            }
            float npc = pc * chh - psn * shh;
            psn = pc * shh + psn * chh;
            pc = npc;
        }
#pragma unroll
        for (int u = 0; u < 5; ++u) {
            if (u < cnt) {
                int ky = kyb + u;
                zsh[h * 17 + ky] = make_float2(aer[u] + aor[u], aei[u] + aoi[u]);
                zsh[(h + 128) * 17 + ky] = make_float2(aer[u] - aor[u], aei[u] - aoi[u]);
            }
        }
    }
    __syncthreads();

    // Phase C: wide read + readlane (z is wave-uniform), ky-fold, hoisted table
    int wv = t >> 6;      // 0..7
    int lane = t & 63;
    float bv = bias[plane & 63];
    float c0, s0;
    sincospif((float)lane * (1.0f / 128.0f), &s0, &c0);  // e^{2pi i lane/256}
    float c8, s8;
    sincospif((float)lane * (1.0f / 16.0f), &s8, &c8);   // e^{2pi i 8 lane/256}

    float pcv[8], psv[8];
    {
        float pc = c0, ps = s0;
#pragma unroll
        for (int k = 0; k < 8; ++k) {
            pcv[k] = pc; psv[k] = ps;
            float nps = fmaf(pc, s0, ps * c0);
            pc = fmaf(pc, c0, -(ps * s0));
            ps = nps;
        }
    }

    const float inv = 1.0f / 65536.0f;
    const float inv2 = 2.0f / 65536.0f;
    long ob_plane = (long)plane * 65536;
    int li = lane < 34 ? lane : 33;

    for (int it16 = 0; it16 < 16; ++it16) {
        int r0 = it16 * 16 + wv * 2;
        // one wide read covers rows r0 and r0+1: zsh[r0*17 + 0..33]
        float2 zl = zsh[r0 * 17 + li];
        float zlx = zl.x, zly = zl.y;

#define RLF(v, l) __int_as_float(__builtin_amdgcn_readlane(__float_as_int(v), (l)))
        float zz0r[8], zz0i[8], zz1r[8], zz1i[8];
#pragma unroll
        for (int k = 0; k < 8; ++k) {
            float a0r = RLF(zlx, k + 1),  a0i = RLF(zly, k + 1);
            float b0r = RLF(zlx, k + 9),  b0i = RLF(zly, k + 9);
            float a1r = RLF(zlx, 18 + k), a1i = RLF(zly, 18 + k);
            float b1r = RLF(zlx, 26 + k), b1i = RLF(zly, 26 + k);
            zz0r[k] = fmaf(b0r, c8, fmaf(-b0i, s8, a0r));
            zz0i[k] = fmaf(b0r, s8, fmaf(b0i, c8, a0i));
            zz1r[k] = fmaf(b1r, c8, fmaf(-b1i, s8, a1r));
            zz1i[k] = fmaf(b1r, s8, fmaf(b1i, c8, a1i));
        }
        float base0 = RLF(zlx, 0) * inv + bv;
        float base1 = RLF(zlx, 17) * inv + bv;
#undef RLF

        float a00 = 0, a01 = 0, a02 = 0, a03 = 0;
        float a10 = 0, a11 = 0, a12 = 0, a13 = 0;
#pragma unroll
        for (int k = 0; k < 8; ++k) {
            int ky = k + 1;
            float A0 = zz0r[k] * pcv[k] - zz0i[k] * psv[k];
            float B0 = zz0r[k] * psv[k] + zz0i[k] * pcv[k];
            float A1 = zz1r[k] * pcv[k] - zz1i[k] * psv[k];
            float B1 = zz1r[k] * psv[k] + zz1i[k] * pcv[k];
            a00 += A0; a10 += A1;
            a01 += ((ky & 3) == 0) ? A0 : ((ky & 3) == 1) ? -B0 : ((ky & 3) == 2) ? -A0 : B0;
            a11 += ((ky & 3) == 0) ? A1 : ((ky & 3) == 1) ? -B1 : ((ky & 3) == 2) ? -A1 : B1;
            a02 += (ky & 1) ? -A0 : A0;
            a12 += (ky & 1) ? -A1 : A1;
            a03 += ((ky & 3) == 0) ? A0 : ((ky & 3) == 1) ? B0 : ((ky & 3) == 2) ? -A0 : -B0;
            a13 += ((ky & 3) == 0) ? A1 : ((ky & 3) == 1) ? B1 : ((ky & 3) == 2) ? -A1 : -B1;
        }
        long ob0 = ob_plane + (long)r0 * 256;
        long ob1 = ob0 + 256;
        out[ob0 + lane]       = fmaf(a00, inv2, base0);
        out[ob0 + 64 + lane]  = fmaf(a01, inv2, base0);
        out[ob0 + 128 + lane] = fmaf(a02, inv2, base0);
        out[ob0 + 192 + lane] = fmaf(a03, inv2, base0);
        out[ob1 + lane]       = fmaf(a10, inv2, base1);
        out[ob1 + 64 + lane]  = fmaf(a11, inv2, base1);
        out[ob1 + 128 + lane] = fmaf(a12, inv2, base1);
        out[ob1 + 192 + lane] = fmaf(a13, inv2, base1);
    }
}

extern "C" void kernel_launch(void* const* d_in, const int* in_sizes, int n_in,
                              void* d_out, int out_size, void* d_ws, size_t ws_size,
                              hipStream_t stream) {
    const float* x = (const float*)d_in[0];
    const float* wr = (const float*)d_in[1];
    const float* wi = (const float*)d_in[2];
    const float* bias = (const float*)d_in[3];
    float* out = (float*)d_out;
    float* ws = (float*)d_ws;

    float2* X2 = (float2*)(ws + 4456960);

    hipLaunchKernelGGL(f1_fw, dim3(512), dim3(512), 0, stream, x, X2);
    hipLaunchKernelGGL(f2c_inv, dim3(512), dim3(512), 0, stream, X2, wr, wi, bias, out);
}

// Round 19
// 110.124 us; speedup vs baseline: 1.0990x; 1.0225x over previous
//
#include <hip/hip_runtime.h>
#include <hip/hip_bf16.h>

// Problem constants
// B=8, C=64, H=256, W=256, NH=4, O=16 (HO=64), MX=32, MY=17
#define NROWS 131072
#define MY 17
#define MX 32

// ws layout (floats):
//   X2:   [4456960, +557056)   [(b*64+c)*32+kx][ky] float2

// ---------------------------------------------------------------------------
// F1 = K1+K2 fused, one (b,c) plane per block, 512 threads. (R8/R14, verified)
// ---------------------------------------------------------------------------
#define K1_ROWS 30
#define NCHUNK 9     // 8*30 + 16 = 256

__global__ __launch_bounds__(512) void f1_fw(const float* __restrict__ x,
                                             float2* __restrict__ X2) {
    __shared__ __align__(16) float s_lds[4][K1_ROWS][68];  // 32640 B
    __shared__ float2 xs[4352];                            // 34816 B  [h*17+ky]
    int t = threadIdx.x;
    int bc = blockIdx.x;  // 0..511
    const float* xp = x + (long)bc * 65536;

    // compute-phase constants: thread t<510: j = t%17, row r = t/17 (0..29)
    int j = t % 17;
    int r = t / 17;
    int rc = r < K1_ROWS ? r : 0;  // clamp for pointer init only
    int odd = j & 1;
    float ca = odd ? 0.f : ((j & 2) ? -1.f : 1.f);
    float cb = odd ? (((j & 3) == 1) ? -1.f : 1.f) : 0.f;
    float cj, sj;
    sincospif((float)j * (1.0f / 128.0f), &sj, &cj);
    sj = -sj;  // step e^{-2pi i j/256}
    float swv, cwv;
    sincospif((float)j * 0.25f, &swv, &cwv);
    swv = -swv;  // w8 = e^{-pi i j/4}
    float k1c = cwv * ca - swv * cb;
    float k2c = swv * ca + cwv * cb;
    const float4* A4 = (const float4*)&s_lds[odd ? 1 : 0][rc][0];
    const float4* B4 = (const float4*)&s_lds[odd ? 3 : 2][rc][0];

    float4 q0, q1, q2, q3;

#define F1_REGLOAD(cc)                                                         \
    {                                                                          \
        int nr_ = ((cc) < 8) ? K1_ROWS : 16;                                   \
        int items_ = nr_ * 16;                                                 \
        int it = t < items_ ? t : items_ - 1;                                  \
        int rr = it >> 4, cq = it & 15;                                        \
        const float4* xr =                                                     \
            (const float4*)(xp + ((cc) * K1_ROWS + rr) * 256) + cq;            \
        q0 = xr[0];                                                            \
        q1 = xr[16];                                                           \
        q2 = xr[32];                                                           \
        q3 = xr[48];                                                           \
    }

    F1_REGLOAD(0)

    for (int c = 0; c < NCHUNK; ++c) {
        int nr = (c < 8) ? K1_ROWS : 16;
        int items = nr * 16;

        // radix-4 combine (along w) + LDS write, from registers
        if (t < items) {
            int rr = t >> 4, cq = t & 15;
            float4 s02p, s02m, s13p, s13m;
            s02p.x = q0.x + q2.x; s02p.y = q0.y + q2.y;
            s02p.z = q0.z + q2.z; s02p.w = q0.w + q2.w;
            s02m.x = q0.x - q2.x; s02m.y = q0.y - q2.y;
            s02m.z = q0.z - q2.z; s02m.w = q0.w - q2.w;
            s13p.x = q1.x + q3.x; s13p.y = q1.y + q3.y;
            s13p.z = q1.z + q3.z; s13p.w = q1.w + q3.w;
            s13m.x = q1.x - q3.x; s13m.y = q1.y - q3.y;
            s13m.z = q1.z - q3.z; s13m.w = q1.w - q3.w;
            *(float4*)&s_lds[0][rr][cq * 4] = s02p;
            *(float4*)&s_lds[1][rr][cq * 4] = s02m;
            *(float4*)&s_lds[2][rr][cq * 4] = s13p;
            *(float4*)&s_lds[3][rr][cq * 4] = s13m;
        }
        __syncthreads();

        // prefetch next chunk into registers (in flight during compute)
        if (c + 1 < NCHUNK) F1_REGLOAD(c + 1)

        // 17-mode DFT of this chunk (radix-2 over l: 32 steps), 1 row/thread
        if (t < 510 && r < nr) {
            float pc = 1.f, ps = 0.f;
            float ar0 = 0, ai0 = 0;

#define K1_STEP(a0e, b0e, a0f, b0f)                                   \
  { float t0re = fmaf(k1c, (b0f), fmaf(cwv, (a0f), fmaf(ca, (b0e), (a0e)))); \
    float t0im = fmaf(k2c, (b0f), fmaf(swv, (a0f), cb * (b0e)));      \
    ar0 = fmaf(t0re, pc, ar0); ar0 = fmaf(-t0im, ps, ar0);            \
    ai0 = fmaf(t0re, ps, ai0); ai0 = fmaf(t0im, pc, ai0);             \
    float nps = fmaf(pc, sj, ps * cj);                                \
    pc = fmaf(pc, cj, -(ps * sj)); ps = nps; }

#pragma unroll 2
            for (int l4 = 0; l4 < 8; ++l4) {
                float4 va0 = A4[l4], vb0 = B4[l4];
                float4 vA0 = A4[8 + l4], vB0 = B4[8 + l4];  // l+32
                K1_STEP(va0.x, vb0.x, vA0.x, vB0.x)
                K1_STEP(va0.y, vb0.y, vA0.y, vB0.y)
                K1_STEP(va0.z, vb0.z, vA0.z, vB0.z)
                K1_STEP(va0.w, vb0.w, vA0.w, vB0.w)
            }
#undef K1_STEP

            int h = c * K1_ROWS + r;
            xs[h * 17 + j] = make_float2(ar0, ai0);
        }
        __syncthreads();
    }

    // K2: in-place radix-4 butterfly along h (stage 1: h vs h+128)
    for (int q = t; q < 2176; q += 512) {
        float2 a = xs[q], b = xs[q + 2176];
        xs[q] = make_float2(a.x + b.x, a.y + b.y);
        xs[q + 2176] = make_float2(a.x - b.x, a.y - b.y);
    }
    __syncthreads();

    for (int q = t; q < 544; q += 512) {
        int kx = q / 17, ky = q % 17;
        int kodd = kx & 1;
        float cA = kodd ? 0.f : ((kx & 2) ? -1.f : 1.f);
        float cB = kodd ? (((kx & 3) == 1) ? -1.f : 1.f) : 0.f;
        float cBn = -cB;
        const float2* Aq = xs + (kodd ? 2176 : 0) + ky;
        float cs, ss;
        sincospif((float)kx * (1.0f / 128.0f), &ss, &cs);
        ss = -ss;  // step e^{-2pi i kx/256}
        float pc = 1.f, psn = 0.f;
        float ar = 0.f, ai = 0.f;
#pragma unroll 4
        for (int m = 0; m < 64; ++m) {
            float2 a = Aq[m * 17];
            float2 b = Aq[1088 + m * 17];
            float yre = fmaf(cBn, b.y, fmaf(cA, b.x, a.x));
            float yim = fmaf(cB, b.x, fmaf(cA, b.y, a.y));
            ar = fmaf(yre, pc, ar); ar = fmaf(-yim, psn, ar);
            ai = fmaf(yre, psn, ai); ai = fmaf(yim, pc, ai);
            float npc = pc * cs - psn * ss;
            psn = pc * ss + psn * cs;
            pc = npc;
        }
        X2[(long)bc * 544 + q] = make_float2(ar, ai);
    }
#undef F1_REGLOAD
}

// ---------------------------------------------------------------------------
// F2C = k3+K4+K5 fused, one (b,ho) plane per block, 512 threads. (R14 exact)
//  + XCD-aware plane swizzle: blocks on XCD k (bi%8==k) own planes 64k..64k+63
//    (one X2 b-plane + weights ~5 MB -> mostly L2-resident phase A).
// ---------------------------------------------------------------------------
__global__ __launch_bounds__(512) void f2c_inv(const float2* __restrict__ X2,
                                               const float* __restrict__ wr_g,
                                               const float* __restrict__ wi_g,
                                               const float* __restrict__ bias,
                                               float* __restrict__ out) {
    __shared__ float2 psh[544];
    __shared__ float2 zsh[4352];  // [h*17+ky]
    int t = threadIdx.x;
    int bi = blockIdx.x;
    int plane = ((bi & 7) << 6) | (bi >> 3);  // bijective XCD swizzle (512%8==0)
    int b = plane >> 6;
    int ho = plane & 63;
    int n = ho >> 4;
    int o = ho & 15;

    // Phase A: per-(kx,ky) 64-deep channel reduction, 2 accumulator pairs
    for (int q = t; q < 544; q += 512) {
        const float2* xp = X2 + (long)b * 64 * 544 + q;
        const float* wrp = wr_g + ((long)(n * 64) * 16 + o) * 544 + q;
        const float* wip = wi_g + ((long)(n * 64) * 16 + o) * 544 + q;
        float ar = 0.f, ai = 0.f, ar2 = 0.f, ai2 = 0.f;
#pragma unroll 4
        for (int i = 0; i < 64; i += 2) {
            float2 xv0 = xp[i * 544];
            float w0r = wrp[i * 8704];
            float w0i = wip[i * 8704];
            float2 xv1 = xp[(i + 1) * 544];
            float w1r = wrp[(i + 1) * 8704];
            float w1i = wip[(i + 1) * 8704];
            ar = fmaf(xv0.x, w0r, fmaf(-xv0.y, w0i, ar));
            ai = fmaf(xv0.x, w0i, fmaf(xv0.y, w0r, ai));
            ar2 = fmaf(xv1.x, w1r, fmaf(-xv1.y, w1i, ar2));
            ai2 = fmaf(xv1.x, w1i, fmaf(xv1.y, w1r, ai2));
        }
        psh[q] = make_float2(ar + ar2, ai + ai2);
    }
    __syncthreads();

    // Phase B: h-pair radix-2 over kx. h = t&127, pair (h, h+128). (verified)
    {
        int h = t & 127;
        int grp = t >> 7;                        // 0..3, wave-uniform
        int kyb = (grp == 0) ? 0 : (4 * grp + 1);  // 0,5,9,13
        int cnt = (grp == 0) ? 5 : 4;
        float chh, shh;
        sincospif((float)h * (1.0f / 128.0f), &shh, &chh);  // step e^{+2pi i h/256}
        float pc = 1.f, psn = 0.f;
        float aer[5], aei[5], aor[5], aoi[5];
#pragma unroll
        for (int u = 0; u < 5; ++u) { aer[u] = 0.f; aei[u] = 0.f; aor[u] = 0.f; aoi[u] = 0.f; }

        const float2* pq = psh + kyb;
#pragma unroll
        for (int kx = 0; kx < 32; ++kx) {
#pragma unroll
            for (int u = 0; u < 5; ++u) {
                if (u < cnt) {
                    float2 v = pq[kx * 17 + u];
                    if ((kx & 1) == 0) {
                        aer[u] = fmaf(v.x, pc, fmaf(-v.y, psn, aer[u]));
                        aei[u] = fmaf(v.x, psn, fmaf(v.y, pc, aei[u]));
                    } else {
                        aor[u] = fmaf(v.x, pc, fmaf(-v.y, psn, aor[u]));
                        aoi[u] = fmaf(v.x, psn, fmaf(v.y, pc, aoi[u]));
                    }
                }
            }
            float npc = pc * chh - psn * shh;
            psn = pc * shh + psn * chh;
            pc = npc;
        }
#pragma unroll
        for (int u = 0; u < 5; ++u) {
            if (u < cnt) {
                int ky = kyb + u;
                zsh[h * 17 + ky] = make_float2(aer[u] + aor[u], aei[u] + aoi[u]);
                zsh[(h + 128) * 17 + ky] = make_float2(aer[u] - aor[u], aei[u] - aoi[u]);
            }
        }
    }
    __syncthreads();

    // Phase C: wide read + readlane (z is wave-uniform), ky-fold, hoisted table
    int wv = t >> 6;      // 0..7
    int lane = t & 63;
    float bv = bias[plane & 63];
    float c0, s0;
    sincospif((float)lane * (1.0f / 128.0f), &s0, &c0);  // e^{2pi i lane/256}
    float c8, s8;
    sincospif((float)lane * (1.0f / 16.0f), &s8, &c8);   // e^{2pi i 8 lane/256}

    float pcv[8], psv[8];
    {
        float pc = c0, ps = s0;
#pragma unroll
        for (int k = 0; k < 8; ++k) {
            pcv[k] = pc; psv[k] = ps;
            float nps = fmaf(pc, s0, ps * c0);
            pc = fmaf(pc, c0, -(ps * s0));
            ps = nps;
        }
    }

    const float inv = 1.0f / 65536.0f;
    const float inv2 = 2.0f / 65536.0f;
    long ob_plane = (long)plane * 65536;
    int li = lane < 34 ? lane : 33;

    for (int it16 = 0; it16 < 16; ++it16) {
        int r0 = it16 * 16 + wv * 2;
        // one wide read covers rows r0 and r0+1: zsh[r0*17 + 0..33]
        float2 zl = zsh[r0 * 17 + li];
        float zlx = zl.x, zly = zl.y;

#define RLF(v, l) __int_as_float(__builtin_amdgcn_readlane(__float_as_int(v), (l)))
        float zz0r[8], zz0i[8], zz1r[8], zz1i[8];
#pragma unroll
        for (int k = 0; k < 8; ++k) {
            float a0r = RLF(zlx, k + 1),  a0i = RLF(zly, k + 1);
            float b0r = RLF(zlx, k + 9),  b0i = RLF(zly, k + 9);
            float a1r = RLF(zlx, 18 + k), a1i = RLF(zly, 18 + k);
            float b1r = RLF(zlx, 26 + k), b1i = RLF(zly, 26 + k);
            zz0r[k] = fmaf(b0r, c8, fmaf(-b0i, s8, a0r));
            zz0i[k] = fmaf(b0r, s8, fmaf(b0i, c8, a0i));
            zz1r[k] = fmaf(b1r, c8, fmaf(-b1i, s8, a1r));
            zz1i[k] = fmaf(b1r, s8, fmaf(b1i, c8, a1i));
        }
        float base0 = RLF(zlx, 0) * inv + bv;
        float base1 = RLF(zlx, 17) * inv + bv;
#undef RLF

        float a00 = 0, a01 = 0, a02 = 0, a03 = 0;
        float a10 = 0, a11 = 0, a12 = 0, a13 = 0;
#pragma unroll
        for (int k = 0; k < 8; ++k) {
            int ky = k + 1;
            float A0 = zz0r[k] * pcv[k] - zz0i[k] * psv[k];
            float B0 = zz0r[k] * psv[k] + zz0i[k] * pcv[k];
            float A1 = zz1r[k] * pcv[k] - zz1i[k] * psv[k];
            float B1 = zz1r[k] * psv[k] + zz1i[k] * pcv[k];
            a00 += A0; a10 += A1;
            a01 += ((ky & 3) == 0) ? A0 : ((ky & 3) == 1) ? -B0 : ((ky & 3) == 2) ? -A0 : B0;
            a11 += ((ky & 3) == 0) ? A1 : ((ky & 3) == 1) ? -B1 : ((ky & 3) == 2) ? -A1 : B1;
            a02 += (ky & 1) ? -A0 : A0;
            a12 += (ky & 1) ? -A1 : A1;
            a03 += ((ky & 3) == 0) ? A0 : ((ky & 3) == 1) ? B0 : ((ky & 3) == 2) ? -A0 : -B0;
            a13 += ((ky & 3) == 0) ? A1 : ((ky & 3) == 1) ? B1 : ((ky & 3) == 2) ? -A1 : -B1;
        }
        long ob0 = ob_plane + (long)r0 * 256;
        long ob1 = ob0 + 256;
        out[ob0 + lane]       = fmaf(a00, inv2, base0);
        out[ob0 + 64 + lane]  = fmaf(a01, inv2, base0);
        out[ob0 + 128 + lane] = fmaf(a02, inv2, base0);
        out[ob0 + 192 + lane] = fmaf(a03, inv2, base0);
        out[ob1 + lane]       = fmaf(a10, inv2, base1);
        out[ob1 + 64 + lane]  = fmaf(a11, inv2, base1);
        out[ob1 + 128 + lane] = fmaf(a12, inv2, base1);
        out[ob1 + 192 + lane] = fmaf(a13, inv2, base1);
    }
}

extern "C" void kernel_launch(void* const* d_in, const int* in_sizes, int n_in,
                              void* d_out, int out_size, void* d_ws, size_t ws_size,
                              hipStream_t stream) {
    const float* x = (const float*)d_in[0];
    const float* wr = (const float*)d_in[1];
    const float* wi = (const float*)d_in[2];
    const float* bias = (const float*)d_in[3];
    float* out = (float*)d_out;
    float* ws = (float*)d_ws;

    float2* X2 = (float2*)(ws + 4456960);

    hipLaunchKernelGGL(f1_fw, dim3(512), dim3(512), 0, stream, x, X2);
    hipLaunchKernelGGL(f2c_inv, dim3(512), dim3(512), 0, stream, X2, wr, wi, bias, out);
}